// Round 7
// baseline (1223.331 us; speedup 1.0000x reference)
//
#include <hip/hip_runtime.h>
#include <hip/hip_bf16.h>
#include <stdint.h>

// B=8, S=2048, D=512, H=2, hd=256. All dims hardcoded.
// 6 dispatches: f2b_all -> proj GEMM (merged rgb+event) -> gate
//   -> QKV GEMM (merged; Q*1/16*log2e compact, K/V pre-chunked) -> attn
//   (64 q-rows/wave, dual QK chains, shared K/V frags, 1 block/CU)
//   -> final GEMM (mix fused in A-staging, +residual, f32)

typedef __bf16 bf16_t;
typedef __bf16 bf16x8 __attribute__((ext_vector_type(8)));
typedef float f32x4 __attribute__((ext_vector_type(4)));
typedef float f32x16 __attribute__((ext_vector_type(16)));
typedef unsigned int u32;

typedef void gvoid_t __attribute__((address_space(1)));
typedef void svoid_t __attribute__((address_space(3)));

__device__ inline void gload16(const void* g, void* l) {
    __builtin_amdgcn_global_load_lds((gvoid_t*)g, (svoid_t*)l, 16, 0, 0);
}

__device__ inline u32 cvtpk_bf16(float lo, float hi) {
    u32 r;
    asm("v_cvt_pk_bf16_f32 %0, %1, %2" : "=v"(r) : "v"(lo), "v"(hi));
    return r;
}

__device__ inline float exp2v(float x) {
    float r;
    asm("v_exp_f32 %0, %1" : "=v"(r) : "v"(x));
    return r;
}

// ---------------- all f32 -> bf16 converts in one dispatch ----------------
__global__ __launch_bounds__(256) void f2b_all(const float* __restrict__ s0, bf16_t* __restrict__ d0,
                                               const float* __restrict__ s1, bf16_t* __restrict__ d1,
                                               const float* __restrict__ s2, bf16_t* __restrict__ d2,
                                               const float* __restrict__ s3, bf16_t* __restrict__ d3,
                                               const float* __restrict__ s4, bf16_t* __restrict__ d4,
                                               const float* __restrict__ s5, bf16_t* __restrict__ d5) {
    int i = blockIdx.x * 256 + threadIdx.x;
    const float* s; bf16_t* d; int off;
    if (i < 1048576)      { s = s0; d = d0; off = i; }
    else if (i < 2097152) { s = s1; d = d1; off = i - 1048576; }
    else if (i < 2129920) { s = s2; d = d2; off = i - 2097152; }
    else if (i < 2162688) { s = s3; d = d3; off = i - 2129920; }
    else if (i < 2260992) { s = s4; d = d4; off = i - 2162688; }
    else                  { s = s5; d = d5; off = i - 2260992; }
    const float4* p = reinterpret_cast<const float4*>(s) + (size_t)off * 2;
    float4 a = p[0], b = p[1];
    bf16x8 o;
    o[0] = (bf16_t)a.x; o[1] = (bf16_t)a.y; o[2] = (bf16_t)a.z; o[3] = (bf16_t)a.w;
    o[4] = (bf16_t)b.x; o[5] = (bf16_t)b.y; o[6] = (bf16_t)b.z; o[7] = (bf16_t)b.w;
    reinterpret_cast<bf16x8*>(d)[off] = o;
}

// ---------------- GEMM: C = A @ B^T, 128x128 tile, BK=64, 4 waves ----------
// MODE 0 (proj, merged): blockIdx.y<128 -> (A,Bw,bias,C); else second set
// MODE 1 (QKV, merged): Q -> qdst[row][col]*(1/16*log2e);
//                       K -> kdst chunked [bh][kt][c=d/8][r=seq%32][e=d%8]
//                       V -> vdst chunked [bh][kt][kc=(seq%32)/8][d][e=seq%8]
// MODE 2 (final): A-staging = gate-mix of A,A2; f32 out + residual
template <int MODE>
__global__ __launch_bounds__(256) void gemm_bt(const bf16_t* __restrict__ A,
                                               const bf16_t* __restrict__ A2,
                                               const bf16_t* __restrict__ Bw,
                                               const bf16_t* __restrict__ Bw2,
                                               const float* __restrict__ bias,
                                               const float* __restrict__ bias2,
                                               void* __restrict__ Cout,
                                               void* __restrict__ Cout2,
                                               const bf16_t* __restrict__ r1,
                                               const bf16_t* __restrict__ r2,
                                               const float* __restrict__ gate,
                                               bf16_t* __restrict__ qdst,
                                               bf16_t* __restrict__ kdst,
                                               bf16_t* __restrict__ vdst,
                                               bf16_t* __restrict__ qdst2,
                                               bf16_t* __restrict__ kdst2,
                                               bf16_t* __restrict__ vdst2,
                                               int N, int K) {
    __shared__ __align__(16) bf16_t As[128][64];
    __shared__ __align__(16) bf16_t Bs[128][64];
    const int tid = threadIdx.x, lane = tid & 63, w = tid >> 6;
    const int l16 = lane & 15, l4 = lane >> 4;
    const int wm = w >> 1, wn = w & 1;
    const bool sec = (MODE != 2) && (blockIdx.y >= 128);
    const size_t a0 = (size_t)(blockIdx.y & 127) * 128;
    const size_t b0 = (size_t)blockIdx.x * 128;
    const bf16_t* Ap = sec ? A2 : A;
    const bf16_t* Bp = sec ? Bw2 : Bw;
    const float* bp = sec ? bias2 : bias;
    f32x4 acc[4][4] = {};
    const int srow = w * 32 + (lane >> 3);
    const int scol = (lane & 7) * 8;
    float g4[4];
    if (MODE == 2) {
#pragma unroll
        for (int i = 0; i < 4; ++i) g4[i] = gate[a0 + srow + i * 8];
    }
    for (int kt = 0; kt < K; kt += 64) {
        __syncthreads();
        if (MODE == 2) {
#pragma unroll
            for (int i = 0; i < 4; ++i) {
                size_t ro = (a0 + srow + i * 8) * (size_t)K + kt + scol;
                bf16x8 x = *reinterpret_cast<const bf16x8*>(A + ro);
                bf16x8 y = *reinterpret_cast<const bf16x8*>(A2 + ro);
                bf16x8 o;
#pragma unroll
                for (int j = 0; j < 8; ++j)
                    o[j] = (bf16_t)(g4[i] * (float)x[j] + (1.f - g4[i]) * (float)y[j]);
                *reinterpret_cast<bf16x8*>(&As[srow + i * 8][scol]) = o;
            }
        } else {
#pragma unroll
            for (int i = 0; i < 4; ++i)
                gload16(Ap + (a0 + srow + i * 8) * (size_t)K + kt + scol, &As[w * 32 + i * 8][0]);
        }
#pragma unroll
        for (int i = 0; i < 4; ++i)
            gload16(Bp + (b0 + srow + i * 8) * (size_t)K + kt + scol, &Bs[w * 32 + i * 8][0]);
        __syncthreads();
#pragma unroll
        for (int kk = 0; kk < 2; ++kk) {
            bf16x8 af[4], bfr[4];
#pragma unroll
            for (int mi = 0; mi < 4; ++mi)
                af[mi] = *reinterpret_cast<const bf16x8*>(&As[wm * 64 + mi * 16 + l16][kk * 32 + l4 * 8]);
#pragma unroll
            for (int ni = 0; ni < 4; ++ni)
                bfr[ni] = *reinterpret_cast<const bf16x8*>(&Bs[wn * 64 + ni * 16 + l16][kk * 32 + l4 * 8]);
#pragma unroll
            for (int mi = 0; mi < 4; ++mi)
#pragma unroll
                for (int ni = 0; ni < 4; ++ni)
                    acc[mi][ni] = __builtin_amdgcn_mfma_f32_16x16x32_bf16(af[mi], bfr[ni], acc[mi][ni], 0, 0, 0);
        }
    }
    bf16_t* qd = sec ? qdst2 : qdst;
    bf16_t* kd = sec ? kdst2 : kdst;
    bf16_t* vd = sec ? vdst2 : vdst;
#pragma unroll
    for (int mi = 0; mi < 4; ++mi) {
#pragma unroll
        for (int ni = 0; ni < 4; ++ni) {
            int col = (int)b0 + wn * 64 + ni * 16 + l16;
            float bs = bp[col];
            int row0 = (int)a0 + wm * 64 + mi * 16 + l4 * 4;
            float vv[4];
#pragma unroll
            for (int r = 0; r < 4; ++r) vv[r] = acc[mi][ni][r] + bs;
            if (MODE == 0) {
                bf16_t* Cp = (bf16_t*)(sec ? Cout2 : Cout);
#pragma unroll
                for (int r = 0; r < 4; ++r)
                    Cp[(size_t)(row0 + r) * N + col] = (bf16_t)vv[r];
            } else if (MODE == 2) {
#pragma unroll
                for (int r = 0; r < 4; ++r) {
                    size_t idx = (size_t)(row0 + r) * N + col;
                    ((float*)Cout)[idx] = vv[r] + 0.5f * ((float)r1[idx] + (float)r2[idx]);
                }
            } else {
                if (col < 512) {
#pragma unroll
                    for (int r = 0; r < 4; ++r)
                        qd[(size_t)(row0 + r) * 512 + col] = (bf16_t)(vv[r] * 0.090168440f);
                } else if (col < 1024) {
                    int cc = col - 512, h = cc >> 8, d = cc & 255;
#pragma unroll
                    for (int r = 0; r < 4; ++r) {
                        int row = row0 + r;
                        int bh = (row >> 11) * 2 + h, seq = row & 2047;
                        kd[((size_t)(bh * 64 + (seq >> 5))) * 8192 + (d >> 3) * 256 +
                           (seq & 31) * 8 + (d & 7)] = (bf16_t)vv[r];
                    }
                } else {
                    int cc = col - 1024, h = cc >> 8, d = cc & 255;
                    int bh = (row0 >> 11) * 2 + h, seq = row0 & 2047;
                    size_t idx = ((size_t)(bh * 64 + (seq >> 5))) * 8192 +
                                 ((seq >> 3) & 3) * 2048 + d * 8 + (seq & 7);
                    union { bf16_t h4[4]; uint2 u8; } pk;
#pragma unroll
                    for (int r = 0; r < 4; ++r) pk.h4[r] = (bf16_t)vv[r];
                    *reinterpret_cast<uint2*>(&vd[idx]) = pk.u8;
                }
            }
        }
    }
}

// ---------------- gate = sigmoid(sum(rgb_p*event_p, axis=-1)) ----------------
__global__ __launch_bounds__(256) void gate_kernel(const bf16_t* __restrict__ rp,
                                                   const bf16_t* __restrict__ ep,
                                                   float* __restrict__ gate) {
    int row = blockIdx.x * 4 + (threadIdx.x >> 6);
    int lane = threadIdx.x & 63;
    bf16x8 a = reinterpret_cast<const bf16x8*>(rp + (size_t)row * 512)[lane];
    bf16x8 b = reinterpret_cast<const bf16x8*>(ep + (size_t)row * 512)[lane];
    float s = 0.f;
#pragma unroll
    for (int j = 0; j < 8; ++j) s += (float)a[j] * (float)b[j];
#pragma unroll
    for (int off = 32; off; off >>= 1) s += __shfl_xor(s, off, 64);
    if (lane == 0) gate[row] = 1.f / (1.f + __expf(-s));
}

// ---------------- flash attention: 64 q-rows per wave ----------------
// grid 256: bid = qb*32 + dir*16 + bh. 4 waves, block owns 256 q rows, KVBLK=32.
// 1 block/CU. Each K/V fragment read once feeds BOTH q-groups (dual chains).
// K LDS [c=32][r=32][8e], V LDS [kc=4][d=256][8e]: base+imm reads, conflict-free.
__global__ __launch_bounds__(256, 1) void attn_kernel(const bf16_t* __restrict__ qbr,
                                                      const bf16_t* __restrict__ qbe,
                                                      const bf16_t* __restrict__ kbr,
                                                      const bf16_t* __restrict__ kbe,
                                                      const bf16_t* __restrict__ vbr,
                                                      const bf16_t* __restrict__ vbe,
                                                      bf16_t* __restrict__ out0,
                                                      bf16_t* __restrict__ out1) {
    __shared__ __align__(16) bf16_t smem[32768];  // K[2][8192] | V[2][8192]
    const int bid = blockIdx.x;
    const int qb = bid >> 5;
    const int combo = bid & 31;
    const int dir = combo >> 4;
    const int bh = combo & 15;
    const int b = bh >> 1, h = bh & 1;
    const bf16_t* Qb = dir ? qbe : qbr;
    const bf16_t* Kc = dir ? kbr : kbe;
    const bf16_t* Vc = dir ? vbr : vbe;
    bf16_t* osrc = dir ? out1 : out0;
    const int tid = threadIdx.x;
    const int w = tid >> 6, l = tid & 63;
    const int l31 = l & 31, hi = l >> 5;
    const int q0w = qb * 256 + w * 64;

    const bf16_t* qp0 = Qb + ((size_t)(b * 2048 + q0w + l31)) * 512 + h * 256 + hi * 8;
    const bf16_t* qp1 = qp0 + 32 * 512;
    bf16x8 qf0[16], qf1[16];
#pragma unroll
    for (int dch = 0; dch < 16; ++dch) {
        qf0[dch] = *reinterpret_cast<const bf16x8*>(qp0 + dch * 16);
        qf1[dch] = *reinterpret_cast<const bf16x8*>(qp1 + dch * 16);
    }

    f32x16 O0[8] = {}, O1[8] = {};
    float mrun0 = -1e30f, lrun0 = 0.f, mrun1 = -1e30f, lrun1 = 0.f;
    union PA { u32 uw[4]; bf16x8 v; } pa00, pa01, pa10, pa11;

    const bf16_t* kq = Kc + (size_t)bh * 524288 + (w * 2048 + l * 8);
    const bf16_t* vq = Vc + (size_t)bh * 524288 + (w * 2048 + l * 8);

#define STAGE(T, P)                                                    \
    do {                                                               \
        const bf16_t* ks_ = kq + (size_t)(T) * 8192;                   \
        const bf16_t* vs_ = vq + (size_t)(T) * 8192;                   \
        bf16_t* lk_ = &smem[(P) * 8192 + w * 2048];                    \
        bf16_t* lv_ = &smem[16384 + (P) * 8192 + w * 2048];            \
        gload16(ks_, lk_); gload16(ks_ + 512, lk_ + 512);              \
        gload16(ks_ + 1024, lk_ + 1024); gload16(ks_ + 1536, lk_ + 1536); \
        gload16(vs_, lv_); gload16(vs_ + 512, lv_ + 512);              \
        gload16(vs_ + 1024, lv_ + 1024); gload16(vs_ + 1536, lv_ + 1536); \
    } while (0)

#define SOFTMAX(STP, MRUN, LRUN, PA0, PA1, OA)                                \
    do {                                                                      \
        float mx_ = STP[0];                                                   \
        _Pragma("unroll") for (int r_ = 1; r_ < 16; ++r_)                     \
            mx_ = fmaxf(mx_, STP[r_]);                                        \
        mx_ = fmaxf(mx_, __shfl_xor(mx_, 32, 64));                            \
        if (__any(mx_ - MRUN > 8.f)) {                                        \
            float mnew_ = fmaxf(MRUN, mx_);                                   \
            float sc_ = exp2v(MRUN - mnew_);                                  \
            MRUN = mnew_; LRUN *= sc_;                                        \
            _Pragma("unroll") for (int r_ = 0; r_ < 16; ++r_) {               \
                int qr_ = (r_ & 3) + 8 * (r_ >> 2) + 4 * hi;                  \
                float scr_ = __shfl(sc_, qr_, 64);                            \
                _Pragma("unroll") for (int g_ = 0; g_ < 8; ++g_)              \
                    OA[g_][r_] *= scr_;                                       \
            }                                                                 \
        }                                                                     \
        float ls_ = 0.f;                                                      \
        u32 W_[8];                                                            \
        _Pragma("unroll") for (int m_ = 0; m_ < 8; ++m_) {                    \
            float plo_ = exp2v(STP[2 * m_] - MRUN);                           \
            float phi_ = exp2v(STP[2 * m_ + 1] - MRUN);                       \
            ls_ += plo_ + phi_;                                               \
            W_[m_] = cvtpk_bf16(plo_, phi_);                                  \
        }                                                                     \
        ls_ += __shfl_xor(ls_, 32, 64);                                       \
        LRUN += ls_;                                                          \
        {                                                                     \
            u32 t0_ = hi ? W_[0] : W_[2], t1_ = hi ? W_[1] : W_[3];           \
            u32 r0_ = (u32)__shfl_xor((int)t0_, 32, 64);                      \
            u32 r1_ = (u32)__shfl_xor((int)t1_, 32, 64);                      \
            PA0.uw[0] = hi ? r0_ : W_[0]; PA0.uw[1] = hi ? r1_ : W_[1];       \
            PA0.uw[2] = hi ? W_[2] : r0_; PA0.uw[3] = hi ? W_[3] : r1_;       \
        }                                                                     \
        {                                                                     \
            u32 t0_ = hi ? W_[4] : W_[6], t1_ = hi ? W_[5] : W_[7];           \
            u32 r0_ = (u32)__shfl_xor((int)t0_, 32, 64);                      \
            u32 r1_ = (u32)__shfl_xor((int)t1_, 32, 64);                      \
            PA1.uw[0] = hi ? r0_ : W_[4]; PA1.uw[1] = hi ? r1_ : W_[5];       \
            PA1.uw[2] = hi ? W_[6] : r0_; PA1.uw[3] = hi ? W_[7] : r1_;       \
        }                                                                     \
    } while (0)

    STAGE(0, 0);

    for (int kt2 = 0; kt2 < 64; ++kt2) {
        asm volatile("s_waitcnt vmcnt(0)" ::: "memory");
        __builtin_amdgcn_s_barrier();
        if (kt2 < 63) STAGE(kt2 + 1, (kt2 + 1) & 1);

        const int cb = kt2 & 1;
        const bf16_t* kb = &smem[cb * 8192 + hi * 256 + l31 * 8];
        const bf16_t* vb = &smem[16384 + cb * 8192 + hi * 2048 + l31 * 8];

        // QK^T (swapped) — each K fragment feeds both q-groups (dual chains)
        f32x16 st0 = {}, st1 = {};
        __builtin_amdgcn_s_setprio(1);
#pragma unroll
        for (int dch = 0; dch < 16; ++dch) {
            bf16x8 kf = *reinterpret_cast<const bf16x8*>(kb + dch * 512);
            st0 = __builtin_amdgcn_mfma_f32_32x32x16_bf16(kf, qf0[dch], st0, 0, 0, 0);
            st1 = __builtin_amdgcn_mfma_f32_32x32x16_bf16(kf, qf1[dch], st1, 0, 0, 0);
        }
        __builtin_amdgcn_s_setprio(0);

        SOFTMAX(st0, mrun0, lrun0, pa00, pa01, O0);
        SOFTMAX(st1, mrun1, lrun1, pa10, pa11, O1);

        // PV — each V fragment feeds both q-groups
        __builtin_amdgcn_s_setprio(1);
#pragma unroll
        for (int g = 0; g < 8; ++g) {
            bf16x8 v0 = *reinterpret_cast<const bf16x8*>(vb + g * 256);
            O0[g] = __builtin_amdgcn_mfma_f32_32x32x16_bf16(pa00.v, v0, O0[g], 0, 0, 0);
            O1[g] = __builtin_amdgcn_mfma_f32_32x32x16_bf16(pa10.v, v0, O1[g], 0, 0, 0);
        }
#pragma unroll
        for (int g = 0; g < 8; ++g) {
            bf16x8 v1 = *reinterpret_cast<const bf16x8*>(vb + 4096 + g * 256);
            O0[g] = __builtin_amdgcn_mfma_f32_32x32x16_bf16(pa01.v, v1, O0[g], 0, 0, 0);
            O1[g] = __builtin_amdgcn_mfma_f32_32x32x16_bf16(pa11.v, v1, O1[g], 0, 0, 0);
        }
        __builtin_amdgcn_s_setprio(0);
    }
#undef STAGE
#undef SOFTMAX

    // normalize (lrun broadcast per q-row) and store, both groups
#pragma unroll
    for (int r = 0; r < 16; ++r) {
        int qr = (r & 3) + 8 * (r >> 2) + 4 * hi;
        float linv0 = 1.0f / __shfl(lrun0, qr, 64);
        float linv1 = 1.0f / __shfl(lrun1, qr, 64);
        size_t row0 = ((size_t)(b * 2048 + q0w + qr)) * 512 + h * 256 + l31;
        size_t row1 = row0 + (size_t)32 * 512;
#pragma unroll
        for (int g = 0; g < 8; ++g) {
            osrc[row0 + g * 32] = (bf16_t)(O0[g][r] * linv0);
            osrc[row1 + g * 32] = (bf16_t)(O1[g][r] * linv1);
        }
    }
}

extern "C" void kernel_launch(void* const* d_in, const int* in_sizes, int n_in,
                              void* d_out, int out_size, void* d_ws, size_t ws_size,
                              hipStream_t stream) {
    const float* rgb = (const float*)d_in[0];
    const float* event = (const float*)d_in[1];
    const float* w_rgb = (const float*)d_in[2];
    const float* b_rgb = (const float*)d_in[3];
    const float* w_event = (const float*)d_in[4];
    const float* b_event = (const float*)d_in[5];
    const float* w_in = (const float*)d_in[6];
    const float* b_in = (const float*)d_in[7];
    const float* w_out = (const float*)d_in[8];
    const float* b_out = (const float*)d_in[9];
    float* out = (float*)d_out;

    const size_t MB16 = (size_t)16 * 1024 * 1024;
    char* ws = (char*)d_ws;
    bf16_t* wrgb_bf = (bf16_t*)(ws + 0);
    bf16_t* wevt_bf = (bf16_t*)(ws + 524288);
    bf16_t* wout_bf = (bf16_t*)(ws + 1048576);
    bf16_t* win_bf = (bf16_t*)(ws + 1572864);
    float* gate = (float*)(ws + 3145728);
    bf16_t* bufA = (bf16_t*)(ws + 4194304);            // rgb bf16 -> attn out dir0
    bf16_t* bufB = (bf16_t*)(ws + 4194304 + MB16);     // event bf16 -> attn out dir1
    bf16_t* rgbp = (bf16_t*)(ws + 4194304 + 2 * MB16);
    bf16_t* evtp = (bf16_t*)(ws + 4194304 + 3 * MB16);
    bf16_t* qbr  = (bf16_t*)(ws + 4194304 + 4 * MB16);
    bf16_t* qbe  = (bf16_t*)(ws + 4194304 + 5 * MB16);
    bf16_t* kbr  = (bf16_t*)(ws + 4194304 + 6 * MB16);
    bf16_t* kbe  = (bf16_t*)(ws + 4194304 + 7 * MB16);
    bf16_t* vbr  = (bf16_t*)(ws + 4194304 + 8 * MB16);
    bf16_t* vbe  = (bf16_t*)(ws + 4194304 + 9 * MB16);

    dim3 blk(256);
    f2b_all<<<8960, blk, 0, stream>>>(rgb, bufA, event, bufB, w_rgb, wrgb_bf,
                                      w_event, wevt_bf, w_in, win_bf, w_out, wout_bf);
    gemm_bt<0><<<dim3(4, 256), blk, 0, stream>>>(bufA, bufB, wrgb_bf, wevt_bf, b_rgb, b_event,
                                                 rgbp, evtp, nullptr, nullptr, nullptr,
                                                 nullptr, nullptr, nullptr, nullptr, nullptr,
                                                 nullptr, 512, 512);
    gate_kernel<<<4096, blk, 0, stream>>>(rgbp, evtp, gate);
    gemm_bt<1><<<dim3(12, 256), blk, 0, stream>>>(rgbp, evtp, win_bf, win_bf, b_in, b_in,
                                                  nullptr, nullptr, nullptr, nullptr, nullptr,
                                                  qbr, kbr, vbr, qbe, kbe, vbe, 1536, 512);
    attn_kernel<<<256, blk, 0, stream>>>(qbr, qbe, kbr, kbe, vbr, vbe, bufA, bufB);
    gemm_bt<2><<<dim3(4, 128), blk, 0, stream>>>(bufA, bufB, wout_bf, nullptr, b_out, nullptr,
                                                 out, nullptr, rgbp, evtp, gate,
                                                 nullptr, nullptr, nullptr, nullptr, nullptr,
                                                 nullptr, 512, 512);
}

// Round 8
// 352.476 us; speedup vs baseline: 3.4707x; 3.4707x over previous
//
#include <hip/hip_runtime.h>
#include <hip/hip_bf16.h>
#include <stdint.h>

// B=8, S=2048, D=512, H=2, hd=256. All dims hardcoded.
// 6 dispatches: f2b_w (weights only) -> proj GEMM (A = f32 direct, reg-staged
//   convert; merged rgb+event) -> gate -> QKV GEMM (merged, XCD-swizzled grid;
//   Q*1/16*log2e compact, K/V pre-chunked) -> attn (R5 known-good) ->
//   final GEMM (mix fused in A-staging, +residual, f32 out)

typedef __bf16 bf16_t;
typedef __bf16 bf16x8 __attribute__((ext_vector_type(8)));
typedef float f32x4 __attribute__((ext_vector_type(4)));
typedef float f32x16 __attribute__((ext_vector_type(16)));
typedef unsigned int u32;

typedef void gvoid_t __attribute__((address_space(1)));
typedef void svoid_t __attribute__((address_space(3)));

__device__ inline void gload16(const void* g, void* l) {
    __builtin_amdgcn_global_load_lds((gvoid_t*)g, (svoid_t*)l, 16, 0, 0);
}

__device__ inline u32 cvtpk_bf16(float lo, float hi) {
    u32 r;
    asm("v_cvt_pk_bf16_f32 %0, %1, %2" : "=v"(r) : "v"(lo), "v"(hi));
    return r;
}

__device__ inline float exp2v(float x) {
    float r;
    asm("v_exp_f32 %0, %1" : "=v"(r) : "v"(x));
    return r;
}

// ---------------- weights f32 -> bf16 (w_rgb|w_event|w_in|w_out) ------------
__global__ __launch_bounds__(256) void f2b_w(const float* __restrict__ s2, bf16_t* __restrict__ d2,
                                             const float* __restrict__ s3, bf16_t* __restrict__ d3,
                                             const float* __restrict__ s4, bf16_t* __restrict__ d4,
                                             const float* __restrict__ s5, bf16_t* __restrict__ d5) {
    int i = blockIdx.x * 256 + threadIdx.x;
    const float* s; bf16_t* d; int off;
    if (i < 32768)       { s = s2; d = d2; off = i; }
    else if (i < 65536)  { s = s3; d = d3; off = i - 32768; }
    else if (i < 163840) { s = s4; d = d4; off = i - 65536; }
    else                 { s = s5; d = d5; off = i - 163840; }
    const float4* p = reinterpret_cast<const float4*>(s) + (size_t)off * 2;
    float4 a = p[0], b = p[1];
    bf16x8 o;
    o[0] = (bf16_t)a.x; o[1] = (bf16_t)a.y; o[2] = (bf16_t)a.z; o[3] = (bf16_t)a.w;
    o[4] = (bf16_t)b.x; o[5] = (bf16_t)b.y; o[6] = (bf16_t)b.z; o[7] = (bf16_t)b.w;
    reinterpret_cast<bf16x8*>(d)[off] = o;
}

// ---------------- GEMM: C = A @ B^T, 128x128 tile, BK=64, 4 waves ----------
// MODE 0 (proj): A = f32 inputs (reg-staged convert); y<128 rgb else event.
// MODE 1 (QKV, merged, 1-D swizzled grid 3072): Q -> qdst*(1/16*log2e);
//         K -> kdst chunked [bh][kt][c=d/8][r=seq%32][e=d%8];
//         V -> vdst chunked [bh][kt][kc=(seq%32)/8][d][e=seq%8]
// MODE 2 (final): A-staging = gate-mix of A,A2; f32 out + residual
template <int MODE>
__global__ __launch_bounds__(256) void gemm_bt(const float* __restrict__ Af,
                                               const float* __restrict__ Af2,
                                               const bf16_t* __restrict__ A,
                                               const bf16_t* __restrict__ A2,
                                               const bf16_t* __restrict__ Bw,
                                               const bf16_t* __restrict__ Bw2,
                                               const float* __restrict__ bias,
                                               const float* __restrict__ bias2,
                                               void* __restrict__ Cout,
                                               void* __restrict__ Cout2,
                                               const bf16_t* __restrict__ r1,
                                               const bf16_t* __restrict__ r2,
                                               const float* __restrict__ gate,
                                               bf16_t* __restrict__ qdst,
                                               bf16_t* __restrict__ kdst,
                                               bf16_t* __restrict__ vdst,
                                               bf16_t* __restrict__ qdst2,
                                               bf16_t* __restrict__ kdst2,
                                               bf16_t* __restrict__ vdst2,
                                               int N, int K) {
    __shared__ __align__(16) bf16_t As[128][64];
    __shared__ __align__(16) bf16_t Bs[128][64];
    const int tid = threadIdx.x, lane = tid & 63, w = tid >> 6;
    const int l16 = lane & 15, l4 = lane >> 4;
    const int wm = w >> 1, wn = w & 1;
    int xt, yt;
    if (MODE == 1) {
        int bid = blockIdx.x;          // 3072 = 12x * 256y, XCD-grouped
        int xcd = bid & 7, idx = bid >> 3;   // idx 0..383
        yt = xcd + 8 * (idx / 12);           // x-fastest within XCD
        xt = idx % 12;
    } else {
        xt = blockIdx.x; yt = blockIdx.y;
    }
    const bool sec = (MODE != 2) && (yt >= 128);
    const size_t a0 = (size_t)(yt & 127) * 128;
    const size_t b0 = (size_t)xt * 128;
    const bf16_t* Ap = sec ? A2 : A;
    const bf16_t* Bp = sec ? Bw2 : Bw;
    const float* Afp = sec ? Af2 : Af;
    const float* bp = sec ? bias2 : bias;
    f32x4 acc[4][4] = {};
    const int srow = w * 32 + (lane >> 3);
    const int scol = (lane & 7) * 8;
    float g4[4];
    if (MODE == 2) {
#pragma unroll
        for (int i = 0; i < 4; ++i) g4[i] = gate[a0 + srow + i * 8];
    }
    for (int kt = 0; kt < K; kt += 64) {
        __syncthreads();
        if (MODE == 0) {
            // reg-stage f32 -> bf16 convert into LDS
#pragma unroll
            for (int i = 0; i < 4; ++i) {
                const float4* p = reinterpret_cast<const float4*>(
                    Afp + (a0 + srow + i * 8) * (size_t)K + kt + scol);
                float4 x = p[0], y = p[1];
                bf16x8 o;
                o[0] = (bf16_t)x.x; o[1] = (bf16_t)x.y; o[2] = (bf16_t)x.z; o[3] = (bf16_t)x.w;
                o[4] = (bf16_t)y.x; o[5] = (bf16_t)y.y; o[6] = (bf16_t)y.z; o[7] = (bf16_t)y.w;
                *reinterpret_cast<bf16x8*>(&As[srow + i * 8][scol]) = o;
            }
        } else if (MODE == 2) {
#pragma unroll
            for (int i = 0; i < 4; ++i) {
                size_t ro = (a0 + srow + i * 8) * (size_t)K + kt + scol;
                bf16x8 x = *reinterpret_cast<const bf16x8*>(A + ro);
                bf16x8 y = *reinterpret_cast<const bf16x8*>(A2 + ro);
                bf16x8 o;
#pragma unroll
                for (int j = 0; j < 8; ++j)
                    o[j] = (bf16_t)(g4[i] * (float)x[j] + (1.f - g4[i]) * (float)y[j]);
                *reinterpret_cast<bf16x8*>(&As[srow + i * 8][scol]) = o;
            }
        } else {
#pragma unroll
            for (int i = 0; i < 4; ++i)
                gload16(Ap + (a0 + srow + i * 8) * (size_t)K + kt + scol, &As[w * 32 + i * 8][0]);
        }
#pragma unroll
        for (int i = 0; i < 4; ++i)
            gload16(Bp + (b0 + srow + i * 8) * (size_t)K + kt + scol, &Bs[w * 32 + i * 8][0]);
        __syncthreads();
#pragma unroll
        for (int kk = 0; kk < 2; ++kk) {
            bf16x8 af[4], bfr[4];
#pragma unroll
            for (int mi = 0; mi < 4; ++mi)
                af[mi] = *reinterpret_cast<const bf16x8*>(&As[wm * 64 + mi * 16 + l16][kk * 32 + l4 * 8]);
#pragma unroll
            for (int ni = 0; ni < 4; ++ni)
                bfr[ni] = *reinterpret_cast<const bf16x8*>(&Bs[wn * 64 + ni * 16 + l16][kk * 32 + l4 * 8]);
#pragma unroll
            for (int mi = 0; mi < 4; ++mi)
#pragma unroll
                for (int ni = 0; ni < 4; ++ni)
                    acc[mi][ni] = __builtin_amdgcn_mfma_f32_16x16x32_bf16(af[mi], bfr[ni], acc[mi][ni], 0, 0, 0);
        }
    }
    bf16_t* qd = sec ? qdst2 : qdst;
    bf16_t* kd = sec ? kdst2 : kdst;
    bf16_t* vd = sec ? vdst2 : vdst;
#pragma unroll
    for (int mi = 0; mi < 4; ++mi) {
#pragma unroll
        for (int ni = 0; ni < 4; ++ni) {
            int col = (int)b0 + wn * 64 + ni * 16 + l16;
            float bs = bp[col];
            int row0 = (int)a0 + wm * 64 + mi * 16 + l4 * 4;
            float vv[4];
#pragma unroll
            for (int r = 0; r < 4; ++r) vv[r] = acc[mi][ni][r] + bs;
            if (MODE == 0) {
                bf16_t* Cp = (bf16_t*)(sec ? Cout2 : Cout);
#pragma unroll
                for (int r = 0; r < 4; ++r)
                    Cp[(size_t)(row0 + r) * N + col] = (bf16_t)vv[r];
            } else if (MODE == 2) {
#pragma unroll
                for (int r = 0; r < 4; ++r) {
                    size_t idx = (size_t)(row0 + r) * N + col;
                    ((float*)Cout)[idx] = vv[r] + 0.5f * ((float)r1[idx] + (float)r2[idx]);
                }
            } else {
                if (col < 512) {
#pragma unroll
                    for (int r = 0; r < 4; ++r)
                        qd[(size_t)(row0 + r) * 512 + col] = (bf16_t)(vv[r] * 0.090168440f);
                } else if (col < 1024) {
                    int cc = col - 512, h = cc >> 8, d = cc & 255;
#pragma unroll
                    for (int r = 0; r < 4; ++r) {
                        int row = row0 + r;
                        int bh = (row >> 11) * 2 + h, seq = row & 2047;
                        kd[((size_t)(bh * 64 + (seq >> 5))) * 8192 + (d >> 3) * 256 +
                           (seq & 31) * 8 + (d & 7)] = (bf16_t)vv[r];
                    }
                } else {
                    int cc = col - 1024, h = cc >> 8, d = cc & 255;
                    int bh = (row0 >> 11) * 2 + h, seq = row0 & 2047;
                    size_t idx = ((size_t)(bh * 64 + (seq >> 5))) * 8192 +
                                 ((seq >> 3) & 3) * 2048 + d * 8 + (seq & 7);
                    union { bf16_t h4[4]; uint2 u8; } pk;
#pragma unroll
                    for (int r = 0; r < 4; ++r) pk.h4[r] = (bf16_t)vv[r];
                    *reinterpret_cast<uint2*>(&vd[idx]) = pk.u8;
                }
            }
        }
    }
}

// ---------------- gate = sigmoid(sum(rgb_p*event_p, axis=-1)) ----------------
__global__ __launch_bounds__(256) void gate_kernel(const bf16_t* __restrict__ rp,
                                                   const bf16_t* __restrict__ ep,
                                                   float* __restrict__ gate) {
    int row = blockIdx.x * 4 + (threadIdx.x >> 6);
    int lane = threadIdx.x & 63;
    bf16x8 a = reinterpret_cast<const bf16x8*>(rp + (size_t)row * 512)[lane];
    bf16x8 b = reinterpret_cast<const bf16x8*>(ep + (size_t)row * 512)[lane];
    float s = 0.f;
#pragma unroll
    for (int j = 0; j < 8; ++j) s += (float)a[j] * (float)b[j];
#pragma unroll
    for (int off = 32; off; off >>= 1) s += __shfl_xor(s, off, 64);
    if (lane == 0) gate[row] = 1.f / (1.f + __expf(-s));
}

// ---------------- flash attention (R5 known-good) ----------------
// grid 512: bid = qb*32 + dir*16 + bh. 4 waves, wave owns 32 q rows, KVBLK=32.
// K/V double-buffered; one vmcnt(0)+barrier per iter; stage t+1 at body top.
__global__ __launch_bounds__(256, 2) void attn_kernel(const bf16_t* __restrict__ qbr,
                                                      const bf16_t* __restrict__ qbe,
                                                      const bf16_t* __restrict__ kbr,
                                                      const bf16_t* __restrict__ kbe,
                                                      const bf16_t* __restrict__ vbr,
                                                      const bf16_t* __restrict__ vbe,
                                                      bf16_t* __restrict__ out0,
                                                      bf16_t* __restrict__ out1) {
    __shared__ __align__(16) bf16_t smem[32768];  // K[2][8192] | V[2][8192]
    const int bid = blockIdx.x;
    const int qb = bid >> 5;
    const int combo = bid & 31;
    const int dir = combo >> 4;
    const int bh = combo & 15;
    const int b = bh >> 1, h = bh & 1;
    const bf16_t* Qb = dir ? qbe : qbr;
    const bf16_t* Kc = dir ? kbr : kbe;
    const bf16_t* Vc = dir ? vbr : vbe;
    bf16_t* osrc = dir ? out1 : out0;
    const int tid = threadIdx.x;
    const int w = tid >> 6, l = tid & 63;
    const int l31 = l & 31, hi = l >> 5;
    const int q0w = qb * 128 + w * 32;

    const bf16_t* qp = Qb + ((size_t)(b * 2048 + q0w + l31)) * 512 + h * 256 + hi * 8;
    bf16x8 qf[16];
#pragma unroll
    for (int dch = 0; dch < 16; ++dch)
        qf[dch] = *reinterpret_cast<const bf16x8*>(qp + dch * 16);

    f32x16 O[8] = {};
    f32x16 st;
    float mrun = -1e30f, lrun = 0.f;
    union PA { u32 uw[4]; bf16x8 v; } pa0, pa1;

    const bf16_t* kq = Kc + (size_t)bh * 524288 + (w * 2048 + l * 8);
    const bf16_t* vq = Vc + (size_t)bh * 524288 + (w * 2048 + l * 8);

#define STAGE(T, P)                                                    \
    do {                                                               \
        const bf16_t* ks_ = kq + (size_t)(T) * 8192;                   \
        const bf16_t* vs_ = vq + (size_t)(T) * 8192;                   \
        bf16_t* lk_ = &smem[(P) * 8192 + w * 2048];                    \
        bf16_t* lv_ = &smem[16384 + (P) * 8192 + w * 2048];            \
        gload16(ks_, lk_); gload16(ks_ + 512, lk_ + 512);              \
        gload16(ks_ + 1024, lk_ + 1024); gload16(ks_ + 1536, lk_ + 1536); \
        gload16(vs_, lv_); gload16(vs_ + 512, lv_ + 512);              \
        gload16(vs_ + 1024, lv_ + 1024); gload16(vs_ + 1536, lv_ + 1536); \
    } while (0)

    STAGE(0, 0);

    for (int kt2 = 0; kt2 < 64; ++kt2) {
        asm volatile("s_waitcnt vmcnt(0)" ::: "memory");
        __builtin_amdgcn_s_barrier();
        if (kt2 < 63) STAGE(kt2 + 1, (kt2 + 1) & 1);

        const int cb = kt2 & 1;
        const bf16_t* kb = &smem[cb * 8192 + hi * 256 + l31 * 8];
        const bf16_t* vb = &smem[16384 + cb * 8192 + hi * 2048 + l31 * 8];

        // QK^T (swapped): st[r] = S[k=(r&3)+8*(r>>2)+4*hi][q=l31], exp2 domain
#pragma unroll
        for (int r = 0; r < 16; ++r) st[r] = 0.f;
        __builtin_amdgcn_s_setprio(1);
#pragma unroll
        for (int dch = 0; dch < 16; ++dch) {
            bf16x8 kf = *reinterpret_cast<const bf16x8*>(kb + dch * 512);
            st = __builtin_amdgcn_mfma_f32_32x32x16_bf16(kf, qf[dch], st, 0, 0, 0);
        }
        __builtin_amdgcn_s_setprio(0);

        // online softmax (lane-local, q=l31; partner lane ^32 holds other k half)
        float mx = st[0];
#pragma unroll
        for (int r = 1; r < 16; ++r) mx = fmaxf(mx, st[r]);
        mx = fmaxf(mx, __shfl_xor(mx, 32, 64));
        if (__any(mx - mrun > 8.f)) {
            float mnew = fmaxf(mrun, mx);
            float sc = exp2v(mrun - mnew);
            mrun = mnew;
            lrun *= sc;
#pragma unroll
            for (int r = 0; r < 16; ++r) {
                int qr = (r & 3) + 8 * (r >> 2) + 4 * hi;
                float scr = __shfl(sc, qr, 64);
#pragma unroll
                for (int g = 0; g < 8; ++g) O[g][r] *= scr;
            }
        }
        float lsum = 0.f;
        u32 W[8];
#pragma unroll
        for (int m = 0; m < 8; ++m) {
            float plo = exp2v(st[2 * m] - mrun);
            float phi_ = exp2v(st[2 * m + 1] - mrun);
            lsum += plo + phi_;
            W[m] = cvtpk_bf16(plo, phi_);
        }
        lsum += __shfl_xor(lsum, 32, 64);
        lrun += lsum;
        {
            u32 t0 = hi ? W[0] : W[2], t1 = hi ? W[1] : W[3];
            u32 r0 = (u32)__shfl_xor((int)t0, 32, 64);
            u32 r1 = (u32)__shfl_xor((int)t1, 32, 64);
            pa0.uw[0] = hi ? r0 : W[0]; pa0.uw[1] = hi ? r1 : W[1];
            pa0.uw[2] = hi ? W[2] : r0; pa0.uw[3] = hi ? W[3] : r1;
        }
        {
            u32 t0 = hi ? W[4] : W[6], t1 = hi ? W[5] : W[7];
            u32 r0 = (u32)__shfl_xor((int)t0, 32, 64);
            u32 r1 = (u32)__shfl_xor((int)t1, 32, 64);
            pa1.uw[0] = hi ? r0 : W[4]; pa1.uw[1] = hi ? r1 : W[5];
            pa1.uw[2] = hi ? W[6] : r0; pa1.uw[3] = hi ? W[7] : r1;
        }

        // PV
        __builtin_amdgcn_s_setprio(1);
#pragma unroll
        for (int g = 0; g < 8; ++g) {
            bf16x8 v0 = *reinterpret_cast<const bf16x8*>(vb + g * 256);
            O[g] = __builtin_amdgcn_mfma_f32_32x32x16_bf16(pa0.v, v0, O[g], 0, 0, 0);
        }
#pragma unroll
        for (int g = 0; g < 8; ++g) {
            bf16x8 v1 = *reinterpret_cast<const bf16x8*>(vb + 4096 + g * 256);
            O[g] = __builtin_amdgcn_mfma_f32_32x32x16_bf16(pa1.v, v1, O[g], 0, 0, 0);
        }
        __builtin_amdgcn_s_setprio(0);
    }
#undef STAGE

    // normalize (lrun broadcast per q-row) and store
#pragma unroll
    for (int r = 0; r < 16; ++r) {
        int qr = (r & 3) + 8 * (r >> 2) + 4 * hi;
        float linv = 1.0f / __shfl(lrun, qr, 64);
        size_t rowoff = ((size_t)(b * 2048 + q0w + qr)) * 512 + h * 256 + l31;
#pragma unroll
        for (int g = 0; g < 8; ++g)
            osrc[rowoff + g * 32] = (bf16_t)(O[g][r] * linv);
    }
}

extern "C" void kernel_launch(void* const* d_in, const int* in_sizes, int n_in,
                              void* d_out, int out_size, void* d_ws, size_t ws_size,
                              hipStream_t stream) {
    const float* rgb = (const float*)d_in[0];
    const float* event = (const float*)d_in[1];
    const float* w_rgb = (const float*)d_in[2];
    const float* b_rgb = (const float*)d_in[3];
    const float* w_event = (const float*)d_in[4];
    const float* b_event = (const float*)d_in[5];
    const float* w_in = (const float*)d_in[6];
    const float* b_in = (const float*)d_in[7];
    const float* w_out = (const float*)d_in[8];
    const float* b_out = (const float*)d_in[9];
    float* out = (float*)d_out;

    const size_t MB16 = (size_t)16 * 1024 * 1024;
    char* ws = (char*)d_ws;
    bf16_t* wrgb_bf = (bf16_t*)(ws + 0);
    bf16_t* wevt_bf = (bf16_t*)(ws + 524288);
    bf16_t* wout_bf = (bf16_t*)(ws + 1048576);
    bf16_t* win_bf = (bf16_t*)(ws + 1572864);
    float* gate = (float*)(ws + 3145728);
    bf16_t* bufA = (bf16_t*)(ws + 4194304);            // attn out dir0
    bf16_t* bufB = (bf16_t*)(ws + 4194304 + MB16);     // attn out dir1
    bf16_t* rgbp = (bf16_t*)(ws + 4194304 + 2 * MB16);
    bf16_t* evtp = (bf16_t*)(ws + 4194304 + 3 * MB16);
    bf16_t* qbr  = (bf16_t*)(ws + 4194304 + 4 * MB16);
    bf16_t* qbe  = (bf16_t*)(ws + 4194304 + 5 * MB16);
    bf16_t* kbr  = (bf16_t*)(ws + 4194304 + 6 * MB16);
    bf16_t* kbe  = (bf16_t*)(ws + 4194304 + 7 * MB16);
    bf16_t* vbr  = (bf16_t*)(ws + 4194304 + 8 * MB16);
    bf16_t* vbe  = (bf16_t*)(ws + 4194304 + 9 * MB16);

    dim3 blk(256);
    // weights convert only (inputs are consumed as f32 by the proj GEMM)
    f2b_w<<<768, blk, 0, stream>>>(w_rgb, wrgb_bf, w_event, wevt_bf,
                                   w_in, win_bf, w_out, wout_bf);
    // input projections (merged): y<128 -> rgb, y>=128 -> event; A = f32 direct
    gemm_bt<0><<<dim3(4, 256), blk, 0, stream>>>(rgb, event, nullptr, nullptr,
                                                 wrgb_bf, wevt_bf, b_rgb, b_event,
                                                 rgbp, evtp, nullptr, nullptr, nullptr,
                                                 nullptr, nullptr, nullptr, nullptr, nullptr,
                                                 nullptr, 512, 512);
    // gate
    gate_kernel<<<4096, blk, 0, stream>>>(rgbp, evtp, gate);
    // QKV projections (merged, XCD-swizzled 1-D grid) -> Q compact + K/V chunked
    gemm_bt<1><<<3072, blk, 0, stream>>>(nullptr, nullptr, rgbp, evtp, win_bf, win_bf,
                                         b_in, b_in, nullptr, nullptr, nullptr, nullptr,
                                         nullptr, qbr, kbr, vbr, qbe, kbe, vbe, 1536, 512);
    // attention both directions
    attn_kernel<<<512, blk, 0, stream>>>(qbr, qbe, kbr, kbe, vbr, vbe, bufA, bufB);
    // final projection: A-staging = gate-mix(bufA,bufB); f32 out + residual
    gemm_bt<2><<<dim3(4, 128), blk, 0, stream>>>(nullptr, nullptr, bufA, bufB, wout_bf, nullptr,
                                                 b_out, nullptr, out, nullptr, rgbp, evtp, gate,
                                                 nullptr, nullptr, nullptr, nullptr, nullptr,
                                                 nullptr, 512, 512);
}

// Round 10
// 303.302 us; speedup vs baseline: 4.0334x; 1.1621x over previous
//
#include <hip/hip_runtime.h>
#include <hip/hip_bf16.h>
#include <stdint.h>

// B=8, S=2048, D=512, H=2, hd=256. All dims hardcoded.
// 6 dispatches: f2b_w (weights only) -> proj GEMM (A = f32 direct) -> gate
//   -> QKV GEMM (merged, XCD-swizzled; Q/K/V stored FP8 e4m3 in attention-ready
//   layouts, K pre-swizzled) -> attn (FP8 MFMA, half LDS traffic) ->
//   final GEMM (mix fused in A-staging, +residual, f32 out)

typedef __bf16 bf16_t;
typedef __bf16 bf16x8 __attribute__((ext_vector_type(8)));
typedef float f32x4 __attribute__((ext_vector_type(4)));
typedef float f32x16 __attribute__((ext_vector_type(16)));
typedef unsigned int u32;
typedef unsigned char u8;

typedef void gvoid_t __attribute__((address_space(1)));
typedef void svoid_t __attribute__((address_space(3)));

__device__ inline void gload16(const void* g, void* l) {
    __builtin_amdgcn_global_load_lds((gvoid_t*)g, (svoid_t*)l, 16, 0, 0);
}

__device__ inline float exp2v(float x) {
    float r;
    asm("v_exp_f32 %0, %1" : "=v"(r) : "v"(x));
    return r;
}

// hiword selector must be a compile-time literal for the builtin.
template <bool HI>
__device__ inline u32 pk_fp8(float a, float b, u32 old) {
    return (u32)__builtin_amdgcn_cvt_pk_fp8_f32(a, b, (int)old, HI);
}
__device__ inline u8 to_fp8(float a) { return (u8)(pk_fp8<false>(a, a, 0) & 0xff); }
__device__ inline long pk64(u32 lo, u32 hi) {
    return (long)(((unsigned long long)hi << 32) | (unsigned long long)lo);
}
__device__ inline f32x16 mfma_fp8(long a, long b, f32x16 c) {
    return __builtin_amdgcn_mfma_f32_32x32x16_fp8_fp8(a, b, c, 0, 0, 0);
}

// ---------------- weights f32 -> bf16 (w_rgb|w_event|w_in|w_out) ------------
__global__ __launch_bounds__(256) void f2b_w(const float* __restrict__ s2, bf16_t* __restrict__ d2,
                                             const float* __restrict__ s3, bf16_t* __restrict__ d3,
                                             const float* __restrict__ s4, bf16_t* __restrict__ d4,
                                             const float* __restrict__ s5, bf16_t* __restrict__ d5) {
    int i = blockIdx.x * 256 + threadIdx.x;
    const float* s; bf16_t* d; int off;
    if (i < 32768)       { s = s2; d = d2; off = i; }
    else if (i < 65536)  { s = s3; d = d3; off = i - 32768; }
    else if (i < 163840) { s = s4; d = d4; off = i - 65536; }
    else                 { s = s5; d = d5; off = i - 163840; }
    const float4* p = reinterpret_cast<const float4*>(s) + (size_t)off * 2;
    float4 a = p[0], b = p[1];
    bf16x8 o;
    o[0] = (bf16_t)a.x; o[1] = (bf16_t)a.y; o[2] = (bf16_t)a.z; o[3] = (bf16_t)a.w;
    o[4] = (bf16_t)b.x; o[5] = (bf16_t)b.y; o[6] = (bf16_t)b.z; o[7] = (bf16_t)b.w;
    reinterpret_cast<bf16x8*>(d)[off] = o;
}

// ---------------- GEMM: C = A @ B^T, 128x128 tile, BK=64, 4 waves ----------
// MODE 0 (proj): A = f32 inputs (reg-staged convert); y<128 rgb else event.
// MODE 1 (QKV, merged, XCD-swizzled grid 3072), all outputs FP8 e4m3:
//   Q -> qdst[row][512] bytes (natural scale)
//   K -> kdst[bh][kt][r*256 + hi_d*128 + (d>>4)*8 + (d&7)] ^ ((r&7)<<4)
//   V -> vdst[bh][kt][d*32 + hi_k*16 + s*8 + j]   (k = s*16+hi_k*8+j)
// MODE 2 (final): A-staging = gate-mix of A,A2; f32 out + residual
template <int MODE>
__global__ __launch_bounds__(256) void gemm_bt(const float* __restrict__ Af,
                                               const float* __restrict__ Af2,
                                               const bf16_t* __restrict__ A,
                                               const bf16_t* __restrict__ A2,
                                               const bf16_t* __restrict__ Bw,
                                               const bf16_t* __restrict__ Bw2,
                                               const float* __restrict__ bias,
                                               const float* __restrict__ bias2,
                                               void* __restrict__ Cout,
                                               void* __restrict__ Cout2,
                                               const bf16_t* __restrict__ r1,
                                               const bf16_t* __restrict__ r2,
                                               const float* __restrict__ gate,
                                               u8* __restrict__ qdst,
                                               u8* __restrict__ kdst,
                                               u8* __restrict__ vdst,
                                               u8* __restrict__ qdst2,
                                               u8* __restrict__ kdst2,
                                               u8* __restrict__ vdst2,
                                               int N, int K) {
    __shared__ __align__(16) bf16_t As[128][64];
    __shared__ __align__(16) bf16_t Bs[128][64];
    const int tid = threadIdx.x, lane = tid & 63, w = tid >> 6;
    const int l16 = lane & 15, l4 = lane >> 4;
    const int wm = w >> 1, wn = w & 1;
    int xt, yt;
    if (MODE == 1) {
        int bid = blockIdx.x;          // 3072 = 12x * 256y, XCD-grouped
        int xcd = bid & 7, idx = bid >> 3;   // idx 0..383
        yt = xcd + 8 * (idx / 12);           // x-fastest within XCD
        xt = idx % 12;
    } else {
        xt = blockIdx.x; yt = blockIdx.y;
    }
    const bool sec = (MODE != 2) && (yt >= 128);
    const size_t a0 = (size_t)(yt & 127) * 128;
    const size_t b0 = (size_t)xt * 128;
    const bf16_t* Ap = sec ? A2 : A;
    const bf16_t* Bp = sec ? Bw2 : Bw;
    const float* Afp = sec ? Af2 : Af;
    const float* bp = sec ? bias2 : bias;
    f32x4 acc[4][4] = {};
    const int srow = w * 32 + (lane >> 3);
    const int scol = (lane & 7) * 8;
    float g4[4];
    if (MODE == 2) {
#pragma unroll
        for (int i = 0; i < 4; ++i) g4[i] = gate[a0 + srow + i * 8];
    }
    for (int kt = 0; kt < K; kt += 64) {
        __syncthreads();
        if (MODE == 0) {
#pragma unroll
            for (int i = 0; i < 4; ++i) {
                const float4* p = reinterpret_cast<const float4*>(
                    Afp + (a0 + srow + i * 8) * (size_t)K + kt + scol);
                float4 x = p[0], y = p[1];
                bf16x8 o;
                o[0] = (bf16_t)x.x; o[1] = (bf16_t)x.y; o[2] = (bf16_t)x.z; o[3] = (bf16_t)x.w;
                o[4] = (bf16_t)y.x; o[5] = (bf16_t)y.y; o[6] = (bf16_t)y.z; o[7] = (bf16_t)y.w;
                *reinterpret_cast<bf16x8*>(&As[srow + i * 8][scol]) = o;
            }
        } else if (MODE == 2) {
#pragma unroll
            for (int i = 0; i < 4; ++i) {
                size_t ro = (a0 + srow + i * 8) * (size_t)K + kt + scol;
                bf16x8 x = *reinterpret_cast<const bf16x8*>(A + ro);
                bf16x8 y = *reinterpret_cast<const bf16x8*>(A2 + ro);
                bf16x8 o;
#pragma unroll
                for (int j = 0; j < 8; ++j)
                    o[j] = (bf16_t)(g4[i] * (float)x[j] + (1.f - g4[i]) * (float)y[j]);
                *reinterpret_cast<bf16x8*>(&As[srow + i * 8][scol]) = o;
            }
        } else {
#pragma unroll
            for (int i = 0; i < 4; ++i)
                gload16(Ap + (a0 + srow + i * 8) * (size_t)K + kt + scol, &As[w * 32 + i * 8][0]);
        }
#pragma unroll
        for (int i = 0; i < 4; ++i)
            gload16(Bp + (b0 + srow + i * 8) * (size_t)K + kt + scol, &Bs[w * 32 + i * 8][0]);
        __syncthreads();
#pragma unroll
        for (int kk = 0; kk < 2; ++kk) {
            bf16x8 af[4], bfr[4];
#pragma unroll
            for (int mi = 0; mi < 4; ++mi)
                af[mi] = *reinterpret_cast<const bf16x8*>(&As[wm * 64 + mi * 16 + l16][kk * 32 + l4 * 8]);
#pragma unroll
            for (int ni = 0; ni < 4; ++ni)
                bfr[ni] = *reinterpret_cast<const bf16x8*>(&Bs[wn * 64 + ni * 16 + l16][kk * 32 + l4 * 8]);
#pragma unroll
            for (int mi = 0; mi < 4; ++mi)
#pragma unroll
                for (int ni = 0; ni < 4; ++ni)
                    acc[mi][ni] = __builtin_amdgcn_mfma_f32_16x16x32_bf16(af[mi], bfr[ni], acc[mi][ni], 0, 0, 0);
        }
    }
    u8* qd = sec ? qdst2 : qdst;
    u8* kd = sec ? kdst2 : kdst;
    u8* vd = sec ? vdst2 : vdst;
#pragma unroll
    for (int mi = 0; mi < 4; ++mi) {
#pragma unroll
        for (int ni = 0; ni < 4; ++ni) {
            int col = (int)b0 + wn * 64 + ni * 16 + l16;
            float bs = bp[col];
            int row0 = (int)a0 + wm * 64 + mi * 16 + l4 * 4;
            float vv[4];
#pragma unroll
            for (int r = 0; r < 4; ++r) vv[r] = acc[mi][ni][r] + bs;
            if (MODE == 0) {
                bf16_t* Cp = (bf16_t*)(sec ? Cout2 : Cout);
#pragma unroll
                for (int r = 0; r < 4; ++r)
                    Cp[(size_t)(row0 + r) * N + col] = (bf16_t)vv[r];
            } else if (MODE == 2) {
#pragma unroll
                for (int r = 0; r < 4; ++r) {
                    size_t idx = (size_t)(row0 + r) * N + col;
                    ((float*)Cout)[idx] = vv[r] + 0.5f * ((float)r1[idx] + (float)r2[idx]);
                }
            } else {
                if (col < 512) {
#pragma unroll
                    for (int r = 0; r < 4; ++r)
                        qd[(size_t)(row0 + r) * 512 + col] = to_fp8(vv[r]);
                } else if (col < 1024) {
                    int cc = col - 512, hh = cc >> 8, d = cc & 255;
                    int dpart = ((d >> 3) & 1) * 128 + (d >> 4) * 8 + (d & 7);
#pragma unroll
                    for (int r = 0; r < 4; ++r) {
                        int row = row0 + r;
                        int bh = (row >> 11) * 2 + hh, seq = row & 2047;
                        int rr = seq & 31;
                        u32 boff = (u32)(rr * 256 + dpart) ^ (u32)((rr & 7) << 4);
                        kd[((size_t)(bh * 64 + (seq >> 5))) * 8192 + boff] = to_fp8(vv[r]);
                    }
                } else {
                    int cc = col - 1024, hh = cc >> 8, d = cc & 255;
                    int bh = (row0 >> 11) * 2 + hh, seq = row0 & 2047;
                    int k = seq & 31;
                    int s = (k >> 4) & 1, hik = (k >> 3) & 1, j0 = k & 7;
                    u32 wrd = pk_fp8<false>(vv[0], vv[1], 0);
                    wrd = pk_fp8<true>(vv[2], vv[3], wrd);
                    *reinterpret_cast<u32*>(vd + ((size_t)(bh * 64 + (seq >> 5))) * 8192 +
                                            d * 32 + hik * 16 + s * 8 + j0) = wrd;
                }
            }
        }
    }
}

// ---------------- gate = sigmoid(sum(rgb_p*event_p, axis=-1)) ----------------
__global__ __launch_bounds__(256) void gate_kernel(const bf16_t* __restrict__ rp,
                                                   const bf16_t* __restrict__ ep,
                                                   float* __restrict__ gate) {
    int row = blockIdx.x * 4 + (threadIdx.x >> 6);
    int lane = threadIdx.x & 63;
    bf16x8 a = reinterpret_cast<const bf16x8*>(rp + (size_t)row * 512)[lane];
    bf16x8 b = reinterpret_cast<const bf16x8*>(ep + (size_t)row * 512)[lane];
    float s = 0.f;
#pragma unroll
    for (int j = 0; j < 8; ++j) s += (float)a[j] * (float)b[j];
#pragma unroll
    for (int off = 32; off; off >>= 1) s += __shfl_xor(s, off, 64);
    if (lane == 0) gate[row] = 1.f / (1.f + __expf(-s));
}

// ---------------- flash attention, FP8 operands ----------------
// grid 512: bid = qb*32 + dir*16 + bh. 4 waves, wave owns 32 q rows, KVBLK=32.
// K LDS [r][hi][dch][8] XOR-swizzled (written pre-swizzled by QKV epilogue,
// staged linearly -> G21-correct); V LDS [d][hi][s][8]: one b128 feeds 2 MFMAs.
// Scores scaled by (1/16)*log2e in f32 after MFMA (Q kept natural scale in fp8).
__global__ __launch_bounds__(256, 2) void attn_kernel(const u8* __restrict__ qbr,
                                                      const u8* __restrict__ qbe,
                                                      const u8* __restrict__ kbr,
                                                      const u8* __restrict__ kbe,
                                                      const u8* __restrict__ vbr,
                                                      const u8* __restrict__ vbe,
                                                      bf16_t* __restrict__ out0,
                                                      bf16_t* __restrict__ out1) {
    __shared__ __align__(16) u8 smem[32768];  // [2 bufs][K 8192 | V 8192]
    const int bid = blockIdx.x;
    const int qb = bid >> 5;
    const int combo = bid & 31;
    const int dir = combo >> 4;
    const int bh = combo & 15;
    const int b = bh >> 1, h = bh & 1;
    const u8* Qb = dir ? qbe : qbr;
    const u8* Kc = dir ? kbr : kbe;
    const u8* Vc = dir ? vbr : vbe;
    bf16_t* osrc = dir ? out1 : out0;
    const int tid = threadIdx.x;
    const int w = tid >> 6, l = tid & 63;
    const int l31 = l & 31, hi = l >> 5;
    const int q0w = qb * 128 + w * 32;

    // Q fragments: 8 fp8 per dch (elements c = dch*16 + hi*8 + j)
    const u8* qp = Qb + ((size_t)(b * 2048 + q0w + l31)) * 512 + h * 256 + hi * 8;
    uint2 qf[16];
#pragma unroll
    for (int dch = 0; dch < 16; ++dch)
        qf[dch] = *reinterpret_cast<const uint2*>(qp + dch * 16);

    f32x16 O[8] = {};
    float mrun = -1e30f, lrun = 0.f;

    const u8* kq = Kc + (size_t)bh * 524288 + w * 2048 + l * 16;
    const u8* vq = Vc + (size_t)bh * 524288 + w * 2048 + l * 16;

#define STAGE(T, P)                                                          \
    do {                                                                     \
        const u8* ks_ = kq + (size_t)(T) * 8192;                             \
        const u8* vs_ = vq + (size_t)(T) * 8192;                             \
        gload16(ks_, &smem[(P) * 16384 + w * 2048]);                         \
        gload16(ks_ + 1024, &smem[(P) * 16384 + w * 2048 + 1024]);           \
        gload16(vs_, &smem[(P) * 16384 + 8192 + w * 2048]);                  \
        gload16(vs_ + 1024, &smem[(P) * 16384 + 8192 + w * 2048 + 1024]);    \
    } while (0)

    STAGE(0, 0);

    const u32 kx = (u32)((l31 & 7) << 4);
    for (int kt2 = 0; kt2 < 64; ++kt2) {
        asm volatile("s_waitcnt vmcnt(0)" ::: "memory");
        __builtin_amdgcn_s_barrier();
        if (kt2 < 63) STAGE(kt2 + 1, (kt2 + 1) & 1);

        const int cb = kt2 & 1;
        const u8* kbp = &smem[cb * 16384] + l31 * 256 + hi * 128;
        const u8* vg = &smem[cb * 16384 + 8192] + l31 * 32 + hi * 16;

        // QK^T (swapped): one b128 feeds two fp8 MFMAs; st[r] k = (r&3)+8(r>>2)+4hi
        f32x16 st = {};
        __builtin_amdgcn_s_setprio(1);
#pragma unroll
        for (int m = 0; m < 8; ++m) {
            uint4 kk = *reinterpret_cast<const uint4*>(kbp + (((u32)(m << 4)) ^ kx));
            st = mfma_fp8(pk64(kk.x, kk.y), pk64(qf[2 * m].x, qf[2 * m].y), st);
            st = mfma_fp8(pk64(kk.z, kk.w), pk64(qf[2 * m + 1].x, qf[2 * m + 1].y), st);
        }
        __builtin_amdgcn_s_setprio(0);

        // scale into exp2 domain: (1/16)*log2(e)
#pragma unroll
        for (int r = 0; r < 16; ++r) st[r] *= 0.090168440f;

        // online softmax (lane-local, q=l31; partner lane ^32 holds other k half)
        float mx = st[0];
#pragma unroll
        for (int r = 1; r < 16; ++r) mx = fmaxf(mx, st[r]);
        mx = fmaxf(mx, __shfl_xor(mx, 32, 64));
        if (__any(mx - mrun > 8.f)) {
            float mnew = fmaxf(mrun, mx);
            float sc = exp2v(mrun - mnew);
            mrun = mnew;
            lrun *= sc;
#pragma unroll
            for (int r = 0; r < 16; ++r) {
                int qr = (r & 3) + 8 * (r >> 2) + 4 * hi;
                float scr = __shfl(sc, qr, 64);
#pragma unroll
                for (int g = 0; g < 8; ++g) O[g][r] *= scr;
            }
        }
        float p_[16];
        float lsum = 0.f;
#pragma unroll
        for (int r = 0; r < 16; ++r) { p_[r] = exp2v(st[r] - mrun); lsum += p_[r]; }
        lsum += __shfl_xor(lsum, 32, 64);
        lrun += lsum;

        // P -> fp8 A-fragments (k = s*16 + hi*8 + j), built via 2 shfl_xor(32)
        u32 X0 = pk_fp8<false>(p_[0], p_[1], 0);   X0 = pk_fp8<true>(p_[2], p_[3], X0);
        u32 X1 = pk_fp8<false>(p_[4], p_[5], 0);   X1 = pk_fp8<true>(p_[6], p_[7], X1);
        u32 X2 = pk_fp8<false>(p_[8], p_[9], 0);   X2 = pk_fp8<true>(p_[10], p_[11], X2);
        u32 X3 = pk_fp8<false>(p_[12], p_[13], 0); X3 = pk_fp8<true>(p_[14], p_[15], X3);
        u32 E0 = (u32)__shfl_xor((int)(hi ? X0 : X1), 32, 64);
        u32 E1 = (u32)__shfl_xor((int)(hi ? X2 : X3), 32, 64);
        long A0 = pk64(hi ? E0 : X0, hi ? X1 : E0);
        long A1 = pk64(hi ? E1 : X2, hi ? X3 : E1);

        // PV: one b128 V read feeds both k-slot MFMAs per 32-d block
        __builtin_amdgcn_s_setprio(1);
#pragma unroll
        for (int g = 0; g < 8; ++g) {
            uint4 v4 = *reinterpret_cast<const uint4*>(vg + g * 1024);
            O[g] = mfma_fp8(A0, pk64(v4.x, v4.y), O[g]);
            O[g] = mfma_fp8(A1, pk64(v4.z, v4.w), O[g]);
        }
        __builtin_amdgcn_s_setprio(0);
    }
#undef STAGE

    // normalize (lrun broadcast per q-row) and store
#pragma unroll
    for (int r = 0; r < 16; ++r) {
        int qr = (r & 3) + 8 * (r >> 2) + 4 * hi;
        float linv = 1.0f / __shfl(lrun, qr, 64);
        size_t rowoff = ((size_t)(b * 2048 + q0w + qr)) * 512 + h * 256 + l31;
#pragma unroll
        for (int g = 0; g < 8; ++g)
            osrc[rowoff + g * 32] = (bf16_t)(O[g][r] * linv);
    }
}

extern "C" void kernel_launch(void* const* d_in, const int* in_sizes, int n_in,
                              void* d_out, int out_size, void* d_ws, size_t ws_size,
                              hipStream_t stream) {
    const float* rgb = (const float*)d_in[0];
    const float* event = (const float*)d_in[1];
    const float* w_rgb = (const float*)d_in[2];
    const float* b_rgb = (const float*)d_in[3];
    const float* w_event = (const float*)d_in[4];
    const float* b_event = (const float*)d_in[5];
    const float* w_in = (const float*)d_in[6];
    const float* b_in = (const float*)d_in[7];
    const float* w_out = (const float*)d_in[8];
    const float* b_out = (const float*)d_in[9];
    float* out = (float*)d_out;

    const size_t MB16 = (size_t)16 * 1024 * 1024;
    char* ws = (char*)d_ws;
    bf16_t* wrgb_bf = (bf16_t*)(ws + 0);
    bf16_t* wevt_bf = (bf16_t*)(ws + 524288);
    bf16_t* wout_bf = (bf16_t*)(ws + 1048576);
    bf16_t* win_bf = (bf16_t*)(ws + 1572864);
    float* gate = (float*)(ws + 3145728);
    bf16_t* bufA = (bf16_t*)(ws + 4194304);            // attn out dir0
    bf16_t* bufB = (bf16_t*)(ws + 4194304 + MB16);     // attn out dir1
    bf16_t* rgbp = (bf16_t*)(ws + 4194304 + 2 * MB16);
    bf16_t* evtp = (bf16_t*)(ws + 4194304 + 3 * MB16);
    u8* qbr = (u8*)(ws + 4194304 + 4 * MB16);
    u8* qbe = (u8*)(ws + 4194304 + 5 * MB16);
    u8* kbr = (u8*)(ws + 4194304 + 6 * MB16);
    u8* kbe = (u8*)(ws + 4194304 + 7 * MB16);
    u8* vbr = (u8*)(ws + 4194304 + 8 * MB16);
    u8* vbe = (u8*)(ws + 4194304 + 9 * MB16);

    dim3 blk(256);
    // weights convert only (inputs are consumed as f32 by the proj GEMM)
    f2b_w<<<768, blk, 0, stream>>>(w_rgb, wrgb_bf, w_event, wevt_bf,
                                   w_in, win_bf, w_out, wout_bf);
    // input projections (merged): y<128 -> rgb, y>=128 -> event; A = f32 direct
    gemm_bt<0><<<dim3(4, 256), blk, 0, stream>>>(rgb, event, nullptr, nullptr,
                                                 wrgb_bf, wevt_bf, b_rgb, b_event,
                                                 rgbp, evtp, nullptr, nullptr, nullptr,
                                                 nullptr, nullptr, nullptr, nullptr, nullptr,
                                                 nullptr, 512, 512);
    // gate
    gate_kernel<<<4096, blk, 0, stream>>>(rgbp, evtp, gate);
    // QKV projections (merged, XCD-swizzled) -> Q/K/V fp8 attention-ready
    gemm_bt<1><<<3072, blk, 0, stream>>>(nullptr, nullptr, rgbp, evtp, win_bf, win_bf,
                                         b_in, b_in, nullptr, nullptr, nullptr, nullptr,
                                         nullptr, qbr, kbr, vbr, qbe, kbe, vbe, 1536, 512);
    // attention both directions
    attn_kernel<<<512, blk, 0, stream>>>(qbr, qbe, kbr, kbe, vbr, vbe, bufA, bufB);
    // final projection: A-staging = gate-mix(bufA,bufB); f32 out + residual
    gemm_bt<2><<<dim3(4, 128), blk, 0, stream>>>(nullptr, nullptr, bufA, bufB, wout_bf, nullptr,
                                                 b_out, nullptr, out, nullptr, rgbp, evtp, gate,
                                                 nullptr, nullptr, nullptr, nullptr, nullptr,
                                                 nullptr, 512, 512);
}